// Round 9
// baseline (161.213 us; speedup 1.0000x reference)
//
#include <hip/hip_runtime.h>

#define HW 224
#define HW2 50176            // 224*224
#define NCH 64
#define NPIX (4 * HW2)       // 200704 pixels total
#define CONV_OUT_ELEMS (4 * NCH * HW2)
#define ZCAP 8192            // max recorded exact-zero x elements

#define TH 7                 // tile rows -> 32 row-tiles
#define TW 16                // tile cols -> 14 col-tiles; grid 1792 blocks
#define LHH 9                // halo rows
#define LWW 18               // halo cols
#define NPOS 162             // LHH*LWW staged positions
#define NGRAN (NPOS * 8)     // 1296 16B granules (LDS 20736 B -> 7 blocks/CU)

typedef short bf16x8 __attribute__((ext_vector_type(8)));
typedef float f32x4 __attribute__((ext_vector_type(4)));

// fp32 -> bf16 round-to-nearest-even
__device__ __forceinline__ unsigned short f2bf(float f) {
    unsigned u = __float_as_uint(f);
    u += 0x7FFFu + ((u >> 16) & 1u);
    return (unsigned short)(u >> 16);
}

// async 16B global->LDS DMA (no VGPR roundtrip). dst must be wave-uniform;
// each ACTIVE lane deposits at dst + lane*16 (exec-masked, r8-verified).
__device__ __forceinline__ void gload16(const unsigned short* src,
                                        unsigned short* dst_uniform) {
    __builtin_amdgcn_global_load_lds(
        (const __attribute__((address_space(1))) unsigned int*)src,
        (__attribute__((address_space(3))) unsigned int*)dst_uniform,
        16, 0, 0);
}

// ===========================================================================
// MAIN PATH
// ===========================================================================

// Fused prep: blocks [0,3136) do x NCHW fp32 -> NHWC bf16, TWO pixels per
// thread (dwordx2 loads -> full 64B wave segments, G13) + exact-zero
// detection; blocks [3136,3280) do weight prep.
// Weight layout: o = (k*4+mg)*512 + lane*8 + j, lane = n+16q,
//   value = w[co=mg*16+n][ci=(k&1)*32+q*8+j][tap=k>>1]
__global__ __launch_bounds__(256) void prep_fused(
    const float* __restrict__ xf, const float* __restrict__ w,
    unsigned short* __restrict__ xbf, unsigned short* __restrict__ wbufA,
    int* __restrict__ zcnt, unsigned int* __restrict__ zlist)
{
    const int tid = threadIdx.x;
    const int bid = blockIdx.x;

    if (bid >= 3136) {                      // ---- weight prep ----
        const int o = (bid - 3136) * 256 + tid;
        if (o < 18 * 2048) {                // 36864 elems
            const int j    = o & 7;
            const int lane = (o >> 3) & 63;
            const int n    = lane & 15;
            const int q    = lane >> 4;
            const int mg   = (o >> 9) & 3;
            const int k    = o >> 11;       // 0..17
            const int tap  = k >> 1;
            const int half = k & 1;
            const int ci   = half * 32 + q * 8 + j;
            const int co   = mg * 16 + n;
            wbufA[o] = f2bf(w[(co * 64 + ci) * 9 + tap]);
        }
        return;
    }

    // ---- x prep: thread = (pixel-pair, ci-octet); 64 pixels per block ----
    const int pair = bid * 32 + (tid >> 3);
    const int oct  = tid & 7;
    const int pix  = pair * 2;
    const int b    = pix / HW2;
    const int rem  = pix - b * HW2;         // even; rem+1 < HW2 (HW2 even)
    const float* src = xf + (size_t)(b * NCH + oct * 8) * HW2 + rem;

    float2 fv[8];
#pragma unroll
    for (int j = 0; j < 8; ++j)
        fv[j] = *reinterpret_cast<const float2*>(src + (size_t)j * HW2);

    bf16x8 v0, v1;
    bool anyz = false;
#pragma unroll
    for (int j = 0; j < 8; ++j) {
        v0[j] = (short)f2bf(fv[j].x);
        v1[j] = (short)f2bf(fv[j].y);
        anyz |= (fv[j].x == 0.0f) | (fv[j].y == 0.0f);
    }
    *reinterpret_cast<bf16x8*>(xbf + (size_t)pix * 64 + oct * 8) = v0;
    *reinterpret_cast<bf16x8*>(xbf + (size_t)(pix + 1) * 64 + oct * 8) = v1;

    // rare path: exact fp32 zeros feed the histogram fixup
    if (__builtin_expect(anyz, 0)) {
#pragma unroll
        for (int pp = 0; pp < 2; ++pp) {
            const int rr = rem + pp;
            const int yy = rr / HW;
            const int xx = rr - yy * HW;
#pragma unroll
            for (int j = 0; j < 8; ++j) {
                const float f = pp ? fv[j].y : fv[j].x;
                if (f == 0.0f) {
                    const int idx = atomicAdd(zcnt, 1);
                    if (idx < ZCAP) {
                        const int ci = oct * 8 + j;
                        zlist[idx] = ((unsigned)b << 22) | ((unsigned)ci << 16)
                                   | ((unsigned)yy << 8) | (unsigned)xx;
                    }
                }
            }
        }
    }
}

// Conv v7: implicit GEMM on NHWC bf16, async global_load_lds staging.
// 7x16 output tile, 256 threads (4 waves); grid 1792 blocks, LDS 20736 B ->
// 7 blocks/CU (28 waves/CU) and capacity 7*256 = 1792 -> ONE generation with
// deep stage/compute/write overlap across resident blocks.
// XCD-chunked mapping (bijective, 1792 = 8*224): each XCD owns a contiguous
// run of row-tiles so row-neighbors share halo rows in the same L2.
// Swizzle via pre-swizzled SOURCE (T21, r8-verified): LDS dest linear, lane
// s loads global granule (pos, (s&7)^(pos&7)); reads use
// phys16 = pos*8 + (blk^(pos&7)). Row 7 clamped/masked (TH=7).
__global__ __launch_bounds__(256, 7) void conv_fused(
    const unsigned short* __restrict__ xbf,
    const unsigned short* __restrict__ wbufA,
    const float* __restrict__ bias, float* __restrict__ y)
{
    __shared__ alignas(16) unsigned short xs[NPOS * 64];  // 20736 B

    const int tid  = threadIdx.x;
    const int wv   = tid >> 6;
    const int lane = tid & 63;
    const int n    = lane & 15;
    const int q    = lane >> 4;

    // XCD-chunked decomposition: l = (phys&7)*224 + phys>>3; row-tiles
    // consecutive within a chunk.
    const int phys_b = blockIdx.x;
    const int l   = (phys_b & 7) * 224 + (phys_b >> 3);
    const int b   = l / 448;
    const int rm  = l - b * 448;
    const int ct  = rm >> 5;             // 0..13
    const int rt  = rm & 31;             // 0..31
    const int c0  = ct * TW;
    const int r0  = rt * TH;

    // ---- stage halo tile: 1296 granules, 6 async iters (last partial) ----
#pragma unroll
    for (int it = 0; it < 6; ++it) {
        const int s = it * 256 + tid;
        if (it < 5 || s < NGRAN) {
            const int pos = s >> 3;
            const int bq  = s & 7;
            const int rr  = pos / LWW;
            const int cc  = pos - rr * LWW;
            const int gy  = r0 + rr - 1;
            const int gx  = c0 + cc - 1;
            const int blk = bq ^ (pos & 7);
            unsigned short* dstb = xs + (size_t)(it * 256 + wv * 64) * 8;
            if ((unsigned)gy < (unsigned)HW && (unsigned)gx < (unsigned)HW) {
                const unsigned short* src =
                    xbf + ((size_t)(b * HW + gy) * HW + gx) * 64 + blk * 8;
                gload16(src, dstb);
            } else {
                *reinterpret_cast<bf16x8*>(xs + (size_t)s * 8) =
                    (bf16x8){0, 0, 0, 0, 0, 0, 0, 0};
            }
        }
    }
    __syncthreads();   // drains vmcnt (gload_lds) + lgkmcnt (zero fills)

    f32x4 acc[4][2];
#pragma unroll
    for (int mg = 0; mg < 4; ++mg)
#pragma unroll
        for (int g = 0; g < 2; ++g) acc[mg][g] = (f32x4){0.f, 0.f, 0.f, 0.f};

    // tile-row indices for this wave's two row slots (row 7 clamped)
    const int rw0 = 2 * wv;
    const int rw1 = (2 * wv + 1 > TH - 1) ? TH - 1 : 2 * wv + 1;

    // ---- K loop: 9 taps x 2 ci-halves, 8 MFMAs each ----
#pragma unroll
    for (int tap = 0; tap < 9; ++tap) {
        const int dh = tap / 3, dw = tap % 3;
#pragma unroll
        for (int half = 0; half < 2; ++half) {
            const int k = tap * 2 + half;
            bf16x8 a[4];
#pragma unroll
            for (int mg = 0; mg < 4; ++mg)
                a[mg] = *reinterpret_cast<const bf16x8*>(
                    wbufA + (k * 4 + mg) * 512 + lane * 8);
#pragma unroll
            for (int g = 0; g < 2; ++g) {
                const int rI  = g ? rw1 : rw0;
                const int pos = (rI + dh) * LWW + dw + n;
                const int phys = pos * 8 + ((half * 4 + q) ^ (pos & 7));
                const bf16x8 bf =
                    *reinterpret_cast<const bf16x8*>(xs + phys * 8);
#pragma unroll
                for (int mg = 0; mg < 4; ++mg)
                    acc[mg][g] = __builtin_amdgcn_mfma_f32_16x16x32_bf16(
                        a[mg], bf, acc[mg][g], 0, 0, 0);
            }
        }
    }

    // ---- epilogue: C/D col=lane&15 (spatial), row=q*4+reg (co);
    //      c0 multiple of 16 -> full 64B sectors; row slot 7 masked ----
#pragma unroll
    for (int g = 0; g < 2; ++g) {
        const int rtile = 2 * wv + g;
        if (rtile < TH) {
            const int row = r0 + rtile;
            const int col = c0 + n;
#pragma unroll
            for (int mg = 0; mg < 4; ++mg) {
#pragma unroll
                for (int rg = 0; rg < 4; ++rg) {
                    const int co = mg * 16 + q * 4 + rg;
                    y[((size_t)(b * NCH + co) * HW + row) * HW + col] =
                        acc[mg][g][rg] + bias[co];
                }
            }
        }
    }
}

// ===========================================================================
// hist_final: single block. Analytic base histogram per channel (exact,
// including w==0 taps) + exact sparse fixup from the recorded x-zero list.
//   z(b,c,r,s) = #taps k where (input OOB) or (w[c][k]==0) or (x at tap == 0)
// ===========================================================================
__global__ __launch_bounds__(256) void hist_final(
    const float* __restrict__ x, const float* __restrict__ w,
    const int* __restrict__ zcnt, const unsigned int* __restrict__ zlist,
    float* __restrict__ hist)
{
    __shared__ int lh[640];
    const int tid = threadIdx.x;
    for (int i = tid; i < 640; i += 256) lh[i] = 0;
    __syncthreads();

    if (tid < 64) {                         // ---- analytic base, channel=tid
        const int c = tid;
        float wk[9];
#pragma unroll
        for (int k = 0; k < 9; ++k) wk[k] = w[c * 9 + k];
        int bins[10];
#pragma unroll
        for (int k = 0; k < 10; ++k) bins[k] = 0;
#pragma unroll
        for (int rcat = 0; rcat < 3; ++rcat) {
#pragma unroll
            for (int scat = 0; scat < 3; ++scat) {
                int z = 0;
#pragma unroll
                for (int k = 0; k < 9; ++k) {
                    const int kh = k / 3, kw = k % 3;
                    const bool oob =
                        (rcat == 0 && kh == 0) || (rcat == 2 && kh == 2) ||
                        (scat == 0 && kw == 0) || (scat == 2 && kw == 2);
                    z += (oob || wk[k] == 0.0f) ? 1 : 0;
                }
                const int cnt =
                    4 * (rcat == 1 ? 222 : 1) * (scat == 1 ? 222 : 1);
                bins[z] += cnt;
            }
        }
#pragma unroll
        for (int k = 0; k < 10; ++k) lh[c * 10 + k] = bins[k];
    }
    __syncthreads();

    // ---- sparse fixup: pair = (zero-entry e, tap t) -> output pixel ----
    const int L = min(*zcnt, ZCAP);
    for (int p = tid; p < L * 9; p += 256) {
        const int e = p / 9, t = p - e * 9;
        const unsigned ent = zlist[e];
        const int b  = (int)(ent >> 22);
        const int c  = (int)(ent >> 16) & 63;
        const int zy = (int)(ent >> 8) & 255;
        const int zx = (int)ent & 255;
        const int kh = t / 3, kw = t % 3;
        const int r = zy - kh + 1, s = zx - kw + 1;   // affected output pixel
        if ((unsigned)r >= (unsigned)HW || (unsigned)s >= (unsigned)HW)
            continue;
        // dedup: the minimal entry index targeting (b,c,r,s) owns the fixup
        bool first = true;
        for (int e2 = 0; e2 < e && first; ++e2) {
            const unsigned ent2 = zlist[e2];
            if ((ent2 >> 16) == (ent >> 16)) {        // same (b,c)
                const int y2 = (int)(ent2 >> 8) & 255;
                const int x2 = (int)ent2 & 255;
                if ((unsigned)(y2 - r + 1) < 3u && (unsigned)(x2 - s + 1) < 3u)
                    first = false;
            }
        }
        if (!first) continue;

        // recompute exact z_base (no x-zero term) and z_true at (b,c,r,s)
        const float* plane = x + (size_t)(b * NCH + c) * HW2;
        int zb = 0, zt = 0;
#pragma unroll
        for (int k = 0; k < 9; ++k) {
            const int kh2 = k / 3, kw2 = k % 3;
            const int yy = r + kh2 - 1, xx = s + kw2 - 1;
            const bool oob = (unsigned)yy >= (unsigned)HW ||
                             (unsigned)xx >= (unsigned)HW;
            const bool w0 = (w[c * 9 + k] == 0.0f);
            const bool x0 = !oob && (plane[yy * HW + xx] == 0.0f);
            zb += (oob || w0) ? 1 : 0;
            zt += (oob || w0 || x0) ? 1 : 0;
        }
        if (zb != zt) {
            atomicAdd(&lh[c * 10 + zb], -1);
            atomicAdd(&lh[c * 10 + zt], 1);
        }
    }
    __syncthreads();
    for (int i = tid; i < 640; i += 256) hist[i] = (float)lh[i];
}

// ===========================================================================
// FALLBACK PATH (ws too small): round-2 kernels.
// ===========================================================================
__global__ void prep_weights_fb(const float* __restrict__ w,
                                unsigned short* __restrict__ wbuf) {
    const int o = blockIdx.x * 256 + threadIdx.x;
    if (o >= 2 * 9 * 4 * 16 * 32) return;
    const int ci = o & 31;
    const int t1 = o >> 5;
    const int co = t1 & 15;
    const int t2 = t1 >> 4;
    const int mg = t2 & 3;
    const int t3 = t2 >> 2;
    const int tap = t3 % 9;
    const int chunk = t3 / 9;
    wbuf[o] = f2bf(w[((mg * 16 + co) * 64 + (chunk * 32 + ci)) * 9 + tap]);
}

__global__ __launch_bounds__(256, 2) void conv_mfma_fb(
    const float* __restrict__ x, const unsigned short* __restrict__ wbuf,
    const float* __restrict__ bias, float* __restrict__ y)
{
    __shared__ alignas(16) unsigned short xs[340 * 32];
    const int tid  = threadIdx.x;
    const int wv   = tid >> 6;
    const int lane = tid & 63;
    const int n    = lane & 15;
    const int q    = lane >> 4;
    const int c0   = blockIdx.x * 32;
    const int r0   = blockIdx.y * 8;
    const int b    = blockIdx.z;

    f32x4 acc[4][4];
#pragma unroll
    for (int mg = 0; mg < 4; ++mg)
#pragma unroll
        for (int g = 0; g < 4; ++g) acc[mg][g] = (f32x4){0.f, 0.f, 0.f, 0.f};

    for (int chunk = 0; chunk < 2; ++chunk) {
        if (chunk) __syncthreads();
        const int ci0 = chunk * 32;
        for (int i = tid; i < 1360; i += 256) {
            const int ci8 = i / 340;
            const int pos = i - ci8 * 340;
            const int r   = pos / 34;
            const int c   = pos - r * 34;
            const int gy  = r0 + r - 1;
            const int gx  = c0 + c - 1;
            bf16x8 v;
            if ((unsigned)gy < (unsigned)HW && (unsigned)gx < (unsigned)HW) {
                const float* src =
                    x + ((size_t)(b * NCH + ci0 + ci8 * 8) * HW + gy) * HW + gx;
#pragma unroll
                for (int j = 0; j < 8; ++j) v[j] = (short)f2bf(src[(size_t)j * HW2]);
            } else {
#pragma unroll
                for (int j = 0; j < 8; ++j) v[j] = 0;
            }
            *reinterpret_cast<bf16x8*>(&xs[pos * 32 + ci8 * 8]) = v;
        }
        __syncthreads();

#pragma unroll
        for (int tap = 0; tap < 9; ++tap) {
            const int dh = tap / 3, dw = tap % 3;
            bf16x8 a[4];
#pragma unroll
            for (int mg = 0; mg < 4; ++mg) {
                const unsigned short* ap =
                    wbuf + ((chunk * 9 + tap) * 4 + mg) * 512 + n * 32 + q * 8;
                a[mg] = *reinterpret_cast<const bf16x8*>(ap);
            }
#pragma unroll
            for (int g = 0; g < 4; ++g) {
                const int rl = 2 * wv + (g >> 1) + dh;
                const int cl = (g & 1) * 16 + dw + n;
                const bf16x8 bf =
                    *reinterpret_cast<const bf16x8*>(&xs[(rl * 34 + cl) * 32 + q * 8]);
#pragma unroll
                for (int mg = 0; mg < 4; ++mg)
                    acc[mg][g] = __builtin_amdgcn_mfma_f32_16x16x32_bf16(
                        a[mg], bf, acc[mg][g], 0, 0, 0);
            }
        }
    }

#pragma unroll
    for (int g = 0; g < 4; ++g) {
        const int row = r0 + 2 * wv + (g >> 1);
        const int col = c0 + (g & 1) * 16 + n;
#pragma unroll
        for (int mg = 0; mg < 4; ++mg) {
#pragma unroll
            for (int rg = 0; rg < 4; ++rg) {
                const int co = mg * 16 + q * 4 + rg;
                y[((size_t)(b * NCH + co) * HW + row) * HW + col] =
                    acc[mg][g][rg] + bias[co];
            }
        }
    }
}

// hist_v2 (fallback path only): honest full pass over x.
__global__ __launch_bounds__(256) void hist_v2(
    const float* __restrict__ x, const float* __restrict__ w,
    float* __restrict__ hist)
{
    __shared__ int lh[10];
    const int tid = threadIdx.x;
    const int col = tid;                 // active iff < 224
    const int rg  = blockIdx.x;          // 0..7
    const int c   = blockIdx.y;
    const int b   = blockIdx.z;
    if (tid < 10) lh[tid] = 0;
    __syncthreads();

    int h[10];
#pragma unroll
    for (int k = 0; k < 10; ++k) h[k] = 0;

    if (col < HW) {
        const float* plane = x + (size_t)(b * NCH + c) * HW2;
        float wk[9];
#pragma unroll
        for (int k = 0; k < 9; ++k) wk[k] = w[c * 9 + k];

        const bool vl = col > 0, vr = col < HW - 1;
        const int r0 = rg * 28;
        float u0, u1, u2, m0, m1, m2;
        if (r0 > 0) {
            const float* p = plane + (size_t)(r0 - 1) * HW + col;
            u0 = vl ? p[-1] : 0.f; u1 = p[0]; u2 = vr ? p[1] : 0.f;
        } else { u0 = u1 = u2 = 0.f; }
        {
            const float* p = plane + (size_t)r0 * HW + col;
            m0 = vl ? p[-1] : 0.f; m1 = p[0]; m2 = vr ? p[1] : 0.f;
        }

        for (int r = r0; r < r0 + 28; ++r) {
            float d0, d1, d2;
            if (r + 1 < HW) {
                const float* p = plane + (size_t)(r + 1) * HW + col;
                d0 = vl ? p[-1] : 0.f; d1 = p[0]; d2 = vr ? p[1] : 0.f;
            } else { d0 = d1 = d2 = 0.f; }

            int cnt = 0;
            cnt += (u0 * wk[0] != 0.f); cnt += (u1 * wk[1] != 0.f); cnt += (u2 * wk[2] != 0.f);
            cnt += (m0 * wk[3] != 0.f); cnt += (m1 * wk[4] != 0.f); cnt += (m2 * wk[5] != 0.f);
            cnt += (d0 * wk[6] != 0.f); cnt += (d1 * wk[7] != 0.f); cnt += (d2 * wk[8] != 0.f);
            const int z = 9 - cnt;
#pragma unroll
            for (int k = 0; k < 10; ++k) h[k] += (z == k);
            u0 = m0; u1 = m1; u2 = m2; m0 = d0; m1 = d1; m2 = d2;
        }
    }

#pragma unroll
    for (int k = 0; k < 10; ++k) {
        int v = h[k];
        v += __shfl_xor(v, 32); v += __shfl_xor(v, 16); v += __shfl_xor(v, 8);
        v += __shfl_xor(v, 4);  v += __shfl_xor(v, 2);  v += __shfl_xor(v, 1);
        if ((tid & 63) == 0 && v != 0) atomicAdd(&lh[k], v);
    }
    __syncthreads();
    if (tid < 10 && lh[tid] > 0)
        atomicAdd(&hist[c * 10 + tid], (float)lh[tid]);
}

// ===========================================================================
extern "C" void kernel_launch(void* const* d_in, const int* in_sizes, int n_in,
                              void* d_out, int out_size, void* d_ws, size_t ws_size,
                              hipStream_t stream) {
    const float* x    = (const float*)d_in[0];
    const float* w    = (const float*)d_in[1];
    const float* bias = (const float*)d_in[2];
    float* y    = (float*)d_out;
    float* hist = (float*)d_out + CONV_OUT_ELEMS;

    const size_t XBF_OFF = 73728;                              // wbufA bytes
    const size_t ZC_OFF  = XBF_OFF + (size_t)NPIX * 64 * 2;    // 25,763,840
    const size_t ZL_OFF  = ZC_OFF + 64;
    const size_t NEED    = ZL_OFF + (size_t)ZCAP * 4;          // ~25.8 MB

    if (ws_size >= NEED) {
        unsigned short* wbufA = (unsigned short*)d_ws;          // 73728 B
        unsigned short* xbf   = (unsigned short*)((char*)d_ws + XBF_OFF);
        int* zcnt             = (int*)((char*)d_ws + ZC_OFF);
        unsigned int* zlist   = (unsigned int*)((char*)d_ws + ZL_OFF);

        hipMemsetAsync(zcnt, 0, sizeof(int), stream);
        prep_fused<<<3280, 256, 0, stream>>>(x, w, xbf, wbufA, zcnt, zlist);
        conv_fused<<<1792, 256, 0, stream>>>(xbf, wbufA, bias, y);
        hist_final<<<1, 256, 0, stream>>>(x, w, zcnt, zlist, hist);
    } else {
        hipMemsetAsync(hist, 0, 64 * 10 * sizeof(float), stream);
        unsigned short* wbuf = (unsigned short*)d_ws;
        prep_weights_fb<<<144, 256, 0, stream>>>(w, wbuf);
        conv_mfma_fb<<<dim3(7, 28, 4), 256, 0, stream>>>(x, wbuf, bias, y);
        hist_v2<<<dim3(8, 64, 4), 256, 0, stream>>>(x, w, hist);
    }
}

// Round 10
// 125.577 us; speedup vs baseline: 1.2838x; 1.2838x over previous
//
#include <hip/hip_runtime.h>

#define HW 224
#define HW2 50176            // 224*224
#define NCH 64
#define NPIX (4 * HW2)       // 200704 pixels total
#define CONV_OUT_ELEMS (4 * NCH * HW2)
#define ZCAP 8192            // max recorded exact-zero x elements

#define TH 7                 // tile rows -> 32 row-tiles
#define TW 32                // tile cols -> 7 col-tiles; grid 896 blocks
#define LHH 9                // halo rows
#define LWW 34               // halo cols
#define NPOS 306             // LHH*LWW staged positions
#define NGRAN (NPOS * 8)     // 2448 16B granules (LDS 39168 B -> 4 blocks/CU)

typedef short bf16x8 __attribute__((ext_vector_type(8)));
typedef float f32x4 __attribute__((ext_vector_type(4)));

// fp32 -> bf16 round-to-nearest-even
__device__ __forceinline__ unsigned short f2bf(float f) {
    unsigned u = __float_as_uint(f);
    u += 0x7FFFu + ((u >> 16) & 1u);
    return (unsigned short)(u >> 16);
}

// async 16B global->LDS DMA (no VGPR roundtrip). dst must be wave-uniform;
// each ACTIVE lane deposits at dst + lane*16 (exec-masked, r8-verified).
__device__ __forceinline__ void gload16(const unsigned short* src,
                                        unsigned short* dst_uniform) {
    __builtin_amdgcn_global_load_lds(
        (const __attribute__((address_space(1))) unsigned int*)src,
        (__attribute__((address_space(3))) unsigned int*)dst_uniform,
        16, 0, 0);
}

// ===========================================================================
// MAIN PATH
// ===========================================================================

// Fused prep: blocks [0,1568) do x NCHW fp32 -> NHWC bf16, FOUR pixels per
// thread (float4 loads -> full 128B wave segments per plane, G13) +
// exact-zero detection; blocks [1568,1712) do weight prep.
// Weight layout: o = (k*4+mg)*512 + lane*8 + j, lane = n+16q,
//   value = w[co=mg*16+n][ci=(k&1)*32+q*8+j][tap=k>>1]
__global__ __launch_bounds__(256) void prep_fused(
    const float* __restrict__ xf, const float* __restrict__ w,
    unsigned short* __restrict__ xbf, unsigned short* __restrict__ wbufA,
    int* __restrict__ zcnt, unsigned int* __restrict__ zlist)
{
    const int tid = threadIdx.x;
    const int bid = blockIdx.x;

    if (bid >= 1568) {                      // ---- weight prep ----
        const int o = (bid - 1568) * 256 + tid;
        if (o < 18 * 2048) {                // 36864 elems
            const int j    = o & 7;
            const int lane = (o >> 3) & 63;
            const int n    = lane & 15;
            const int q    = lane >> 4;
            const int mg   = (o >> 9) & 3;
            const int k    = o >> 11;       // 0..17
            const int tap  = k >> 1;
            const int half = k & 1;
            const int ci   = half * 32 + q * 8 + j;
            const int co   = mg * 16 + n;
            wbufA[o] = f2bf(w[(co * 64 + ci) * 9 + tap]);
        }
        return;
    }

    // ---- x prep: thread = (pixel-quad, ci-octet); 128 pixels per block ----
    const int quad = bid * 32 + (tid >> 3);
    const int oct  = tid & 7;
    const int pix  = quad * 4;
    const int b    = pix / HW2;
    const int rem  = pix - b * HW2;         // multiple of 4 (4 | HW2)
    const float* src = xf + (size_t)(b * NCH + oct * 8) * HW2 + rem;

    float4 fv[8];
#pragma unroll
    for (int j = 0; j < 8; ++j)
        fv[j] = *reinterpret_cast<const float4*>(src + (size_t)j * HW2);

    bf16x8 v[4];
    bool anyz = false;
#pragma unroll
    for (int j = 0; j < 8; ++j) {
        v[0][j] = (short)f2bf(fv[j].x);
        v[1][j] = (short)f2bf(fv[j].y);
        v[2][j] = (short)f2bf(fv[j].z);
        v[3][j] = (short)f2bf(fv[j].w);
        anyz |= (fv[j].x == 0.0f) | (fv[j].y == 0.0f) |
                (fv[j].z == 0.0f) | (fv[j].w == 0.0f);
    }
#pragma unroll
    for (int pp = 0; pp < 4; ++pp)
        *reinterpret_cast<bf16x8*>(xbf + (size_t)(pix + pp) * 64 + oct * 8) =
            v[pp];

    // rare path: exact fp32 zeros feed the histogram fixup
    if (__builtin_expect(anyz, 0)) {
#pragma unroll
        for (int pp = 0; pp < 4; ++pp) {
            const int rr = rem + pp;
            const int yy = rr / HW;
            const int xx = rr - yy * HW;
#pragma unroll
            for (int j = 0; j < 8; ++j) {
                const float f = pp == 0 ? fv[j].x : pp == 1 ? fv[j].y
                              : pp == 2 ? fv[j].z : fv[j].w;
                if (f == 0.0f) {
                    const int idx = atomicAdd(zcnt, 1);
                    if (idx < ZCAP) {
                        const int ci = oct * 8 + j;
                        zlist[idx] = ((unsigned)b << 22) | ((unsigned)ci << 16)
                                   | ((unsigned)yy << 8) | (unsigned)xx;
                    }
                }
            }
        }
    }
}

// Conv v8 = r8's proven conv (TW=32: 128B write segments, WRITE_SIZE exact)
// + r9's proven XCD-chunked mapping (FETCH 26.5 MB via halo-row L2 reuse).
// 7x32 output tile, 256 threads (4 waves), 896 blocks, LDS 39168 B ->
// 4 blocks/CU -> capacity 1024 >= 896 -> ONE generation.
// Bijective chunking (896 = 8*112): XCD k owns l in [k*112,(k+1)*112);
// consecutive l = consecutive row-tiles at one col-tile -> shared halo rows.
// Swizzle via pre-swizzled SOURCE (T21): LDS dest linear, lane s loads
// global granule (pos, (s&7)^(pos&7)); reads use phys16 = pos*8+(blk^(pos&7)).
__global__ __launch_bounds__(256, 4) void conv_fused(
    const unsigned short* __restrict__ xbf,
    const unsigned short* __restrict__ wbufA,
    const float* __restrict__ bias, float* __restrict__ y)
{
    __shared__ alignas(16) unsigned short xs[NPOS * 64];  // 39168 B

    const int tid  = threadIdx.x;
    const int wv   = tid >> 6;
    const int lane = tid & 63;
    const int n    = lane & 15;
    const int q    = lane >> 4;

    // XCD-chunked decomposition (bijective: 896 = 8 XCDs x 112)
    const int phys_b = blockIdx.x;
    const int l   = (phys_b & 7) * 112 + (phys_b >> 3);
    const int b   = l / 224;
    const int rm  = l - b * 224;
    const int ct  = rm >> 5;             // 0..6
    const int rt  = rm & 31;             // 0..31
    const int c0  = ct * TW;
    const int r0  = rt * TH;

    // ---- stage halo tile: 2448 granules, 10 async iters (last partial) ----
#pragma unroll
    for (int it = 0; it < 10; ++it) {
        const int s = it * 256 + tid;
        if (it < 9 || s < NGRAN) {
            const int pos = s >> 3;
            const int bq  = s & 7;
            const int rr  = pos / LWW;
            const int cc  = pos - rr * LWW;
            const int gy  = r0 + rr - 1;
            const int gx  = c0 + cc - 1;
            const int blk = bq ^ (pos & 7);
            unsigned short* dstb = xs + (size_t)(it * 256 + wv * 64) * 8;
            if ((unsigned)gy < (unsigned)HW && (unsigned)gx < (unsigned)HW) {
                const unsigned short* src =
                    xbf + ((size_t)(b * HW + gy) * HW + gx) * 64 + blk * 8;
                gload16(src, dstb);
            } else {
                *reinterpret_cast<bf16x8*>(xs + (size_t)s * 8) =
                    (bf16x8){0, 0, 0, 0, 0, 0, 0, 0};
            }
        }
    }
    __syncthreads();   // drains vmcnt (gload_lds) + lgkmcnt (zero fills)

    f32x4 acc[4][4];
#pragma unroll
    for (int mg = 0; mg < 4; ++mg)
#pragma unroll
        for (int g = 0; g < 4; ++g) acc[mg][g] = (f32x4){0.f, 0.f, 0.f, 0.f};

    // tile-row indices for the two row-groups of this wave (row 7 clamped)
    const int rw0 = 2 * wv;
    const int rw1 = (2 * wv + 1 > TH - 1) ? TH - 1 : 2 * wv + 1;

    // ---- K loop: 9 taps x 2 ci-halves, 16 MFMAs each ----
#pragma unroll
    for (int tap = 0; tap < 9; ++tap) {
        const int dh = tap / 3, dw = tap % 3;
#pragma unroll
        for (int half = 0; half < 2; ++half) {
            const int k = tap * 2 + half;
            bf16x8 a[4];
#pragma unroll
            for (int mg = 0; mg < 4; ++mg)
                a[mg] = *reinterpret_cast<const bf16x8*>(
                    wbufA + (k * 4 + mg) * 512 + lane * 8);
#pragma unroll
            for (int g = 0; g < 4; ++g) {
                const int rI  = (g >> 1) ? rw1 : rw0;
                const int pos = (rI + dh) * LWW + (g & 1) * 16 + dw + n;
                const int phys = pos * 8 + ((half * 4 + q) ^ (pos & 7));
                const bf16x8 bf =
                    *reinterpret_cast<const bf16x8*>(xs + phys * 8);
#pragma unroll
                for (int mg = 0; mg < 4; ++mg)
                    acc[mg][g] = __builtin_amdgcn_mfma_f32_16x16x32_bf16(
                        a[mg], bf, acc[mg][g], 0, 0, 0);
            }
        }
    }

    // ---- epilogue: C/D col=lane&15 (spatial), row=q*4+reg (co);
    //      128B contiguous aligned segments; row slot 7 masked (TH=7) ----
#pragma unroll
    for (int g = 0; g < 4; ++g) {
        const int rtile = 2 * wv + (g >> 1);
        if (rtile < TH) {
            const int row = r0 + rtile;
            const int col = c0 + (g & 1) * 16 + n;
#pragma unroll
            for (int mg = 0; mg < 4; ++mg) {
#pragma unroll
                for (int rg = 0; rg < 4; ++rg) {
                    const int co = mg * 16 + q * 4 + rg;
                    y[((size_t)(b * NCH + co) * HW + row) * HW + col] =
                        acc[mg][g][rg] + bias[co];
                }
            }
        }
    }
}

// ===========================================================================
// hist_final: single block. Analytic base histogram per channel (exact,
// including w==0 taps) + exact sparse fixup from the recorded x-zero list.
//   z(b,c,r,s) = #taps k where (input OOB) or (w[c][k]==0) or (x at tap == 0)
// ===========================================================================
__global__ __launch_bounds__(256) void hist_final(
    const float* __restrict__ x, const float* __restrict__ w,
    const int* __restrict__ zcnt, const unsigned int* __restrict__ zlist,
    float* __restrict__ hist)
{
    __shared__ int lh[640];
    const int tid = threadIdx.x;
    for (int i = tid; i < 640; i += 256) lh[i] = 0;
    __syncthreads();

    if (tid < 64) {                         // ---- analytic base, channel=tid
        const int c = tid;
        float wk[9];
#pragma unroll
        for (int k = 0; k < 9; ++k) wk[k] = w[c * 9 + k];
        int bins[10];
#pragma unroll
        for (int k = 0; k < 10; ++k) bins[k] = 0;
#pragma unroll
        for (int rcat = 0; rcat < 3; ++rcat) {
#pragma unroll
            for (int scat = 0; scat < 3; ++scat) {
                int z = 0;
#pragma unroll
                for (int k = 0; k < 9; ++k) {
                    const int kh = k / 3, kw = k % 3;
                    const bool oob =
                        (rcat == 0 && kh == 0) || (rcat == 2 && kh == 2) ||
                        (scat == 0 && kw == 0) || (scat == 2 && kw == 2);
                    z += (oob || wk[k] == 0.0f) ? 1 : 0;
                }
                const int cnt =
                    4 * (rcat == 1 ? 222 : 1) * (scat == 1 ? 222 : 1);
                bins[z] += cnt;
            }
        }
#pragma unroll
        for (int k = 0; k < 10; ++k) lh[c * 10 + k] = bins[k];
    }
    __syncthreads();

    // ---- sparse fixup: pair = (zero-entry e, tap t) -> output pixel ----
    const int L = min(*zcnt, ZCAP);
    for (int p = tid; p < L * 9; p += 256) {
        const int e = p / 9, t = p - e * 9;
        const unsigned ent = zlist[e];
        const int b  = (int)(ent >> 22);
        const int c  = (int)(ent >> 16) & 63;
        const int zy = (int)(ent >> 8) & 255;
        const int zx = (int)ent & 255;
        const int kh = t / 3, kw = t % 3;
        const int r = zy - kh + 1, s = zx - kw + 1;   // affected output pixel
        if ((unsigned)r >= (unsigned)HW || (unsigned)s >= (unsigned)HW)
            continue;
        // dedup: the minimal entry index targeting (b,c,r,s) owns the fixup
        bool first = true;
        for (int e2 = 0; e2 < e && first; ++e2) {
            const unsigned ent2 = zlist[e2];
            if ((ent2 >> 16) == (ent >> 16)) {        // same (b,c)
                const int y2 = (int)(ent2 >> 8) & 255;
                const int x2 = (int)ent2 & 255;
                if ((unsigned)(y2 - r + 1) < 3u && (unsigned)(x2 - s + 1) < 3u)
                    first = false;
            }
        }
        if (!first) continue;

        // recompute exact z_base (no x-zero term) and z_true at (b,c,r,s)
        const float* plane = x + (size_t)(b * NCH + c) * HW2;
        int zb = 0, zt = 0;
#pragma unroll
        for (int k = 0; k < 9; ++k) {
            const int kh2 = k / 3, kw2 = k % 3;
            const int yy = r + kh2 - 1, xx = s + kw2 - 1;
            const bool oob = (unsigned)yy >= (unsigned)HW ||
                             (unsigned)xx >= (unsigned)HW;
            const bool w0 = (w[c * 9 + k] == 0.0f);
            const bool x0 = !oob && (plane[yy * HW + xx] == 0.0f);
            zb += (oob || w0) ? 1 : 0;
            zt += (oob || w0 || x0) ? 1 : 0;
        }
        if (zb != zt) {
            atomicAdd(&lh[c * 10 + zb], -1);
            atomicAdd(&lh[c * 10 + zt], 1);
        }
    }
    __syncthreads();
    for (int i = tid; i < 640; i += 256) hist[i] = (float)lh[i];
}

// ===========================================================================
// FALLBACK PATH (ws too small): round-2 kernels.
// ===========================================================================
__global__ void prep_weights_fb(const float* __restrict__ w,
                                unsigned short* __restrict__ wbuf) {
    const int o = blockIdx.x * 256 + threadIdx.x;
    if (o >= 2 * 9 * 4 * 16 * 32) return;
    const int ci = o & 31;
    const int t1 = o >> 5;
    const int co = t1 & 15;
    const int t2 = t1 >> 4;
    const int mg = t2 & 3;
    const int t3 = t2 >> 2;
    const int tap = t3 % 9;
    const int chunk = t3 / 9;
    wbuf[o] = f2bf(w[((mg * 16 + co) * 64 + (chunk * 32 + ci)) * 9 + tap]);
}

__global__ __launch_bounds__(256, 2) void conv_mfma_fb(
    const float* __restrict__ x, const unsigned short* __restrict__ wbuf,
    const float* __restrict__ bias, float* __restrict__ y)
{
    __shared__ alignas(16) unsigned short xs[340 * 32];
    const int tid  = threadIdx.x;
    const int wv   = tid >> 6;
    const int lane = tid & 63;
    const int n    = lane & 15;
    const int q    = lane >> 4;
    const int c0   = blockIdx.x * 32;
    const int r0   = blockIdx.y * 8;
    const int b    = blockIdx.z;

    f32x4 acc[4][4];
#pragma unroll
    for (int mg = 0; mg < 4; ++mg)
#pragma unroll
        for (int g = 0; g < 4; ++g) acc[mg][g] = (f32x4){0.f, 0.f, 0.f, 0.f};

    for (int chunk = 0; chunk < 2; ++chunk) {
        if (chunk) __syncthreads();
        const int ci0 = chunk * 32;
        for (int i = tid; i < 1360; i += 256) {
            const int ci8 = i / 340;
            const int pos = i - ci8 * 340;
            const int r   = pos / 34;
            const int c   = pos - r * 34;
            const int gy  = r0 + r - 1;
            const int gx  = c0 + c - 1;
            bf16x8 v;
            if ((unsigned)gy < (unsigned)HW && (unsigned)gx < (unsigned)HW) {
                const float* src =
                    x + ((size_t)(b * NCH + ci0 + ci8 * 8) * HW + gy) * HW + gx;
#pragma unroll
                for (int j = 0; j < 8; ++j) v[j] = (short)f2bf(src[(size_t)j * HW2]);
            } else {
#pragma unroll
                for (int j = 0; j < 8; ++j) v[j] = 0;
            }
            *reinterpret_cast<bf16x8*>(&xs[pos * 32 + ci8 * 8]) = v;
        }
        __syncthreads();

#pragma unroll
        for (int tap = 0; tap < 9; ++tap) {
            const int dh = tap / 3, dw = tap % 3;
            bf16x8 a[4];
#pragma unroll
            for (int mg = 0; mg < 4; ++mg) {
                const unsigned short* ap =
                    wbuf + ((chunk * 9 + tap) * 4 + mg) * 512 + n * 32 + q * 8;
                a[mg] = *reinterpret_cast<const bf16x8*>(ap);
            }
#pragma unroll
            for (int g = 0; g < 4; ++g) {
                const int rl = 2 * wv + (g >> 1) + dh;
                const int cl = (g & 1) * 16 + dw + n;
                const bf16x8 bf =
                    *reinterpret_cast<const bf16x8*>(&xs[(rl * 34 + cl) * 32 + q * 8]);
#pragma unroll
                for (int mg = 0; mg < 4; ++mg)
                    acc[mg][g] = __builtin_amdgcn_mfma_f32_16x16x32_bf16(
                        a[mg], bf, acc[mg][g], 0, 0, 0);
            }
        }
    }

#pragma unroll
    for (int g = 0; g < 4; ++g) {
        const int row = r0 + 2 * wv + (g >> 1);
        const int col = c0 + (g & 1) * 16 + n;
#pragma unroll
        for (int mg = 0; mg < 4; ++mg) {
#pragma unroll
            for (int rg = 0; rg < 4; ++rg) {
                const int co = mg * 16 + q * 4 + rg;
                y[((size_t)(b * NCH + co) * HW + row) * HW + col] =
                    acc[mg][g][rg] + bias[co];
            }
        }
    }
}

// hist_v2 (fallback path only): honest full pass over x.
__global__ __launch_bounds__(256) void hist_v2(
    const float* __restrict__ x, const float* __restrict__ w,
    float* __restrict__ hist)
{
    __shared__ int lh[10];
    const int tid = threadIdx.x;
    const int col = tid;                 // active iff < 224
    const int rg  = blockIdx.x;          // 0..7
    const int c   = blockIdx.y;
    const int b   = blockIdx.z;
    if (tid < 10) lh[tid] = 0;
    __syncthreads();

    int h[10];
#pragma unroll
    for (int k = 0; k < 10; ++k) h[k] = 0;

    if (col < HW) {
        const float* plane = x + (size_t)(b * NCH + c) * HW2;
        float wk[9];
#pragma unroll
        for (int k = 0; k < 9; ++k) wk[k] = w[c * 9 + k];

        const bool vl = col > 0, vr = col < HW - 1;
        const int r0 = rg * 28;
        float u0, u1, u2, m0, m1, m2;
        if (r0 > 0) {
            const float* p = plane + (size_t)(r0 - 1) * HW + col;
            u0 = vl ? p[-1] : 0.f; u1 = p[0]; u2 = vr ? p[1] : 0.f;
        } else { u0 = u1 = u2 = 0.f; }
        {
            const float* p = plane + (size_t)r0 * HW + col;
            m0 = vl ? p[-1] : 0.f; m1 = p[0]; m2 = vr ? p[1] : 0.f;
        }

        for (int r = r0; r < r0 + 28; ++r) {
            float d0, d1, d2;
            if (r + 1 < HW) {
                const float* p = plane + (size_t)(r + 1) * HW + col;
                d0 = vl ? p[-1] : 0.f; d1 = p[0]; d2 = vr ? p[1] : 0.f;
            } else { d0 = d1 = d2 = 0.f; }

            int cnt = 0;
            cnt += (u0 * wk[0] != 0.f); cnt += (u1 * wk[1] != 0.f); cnt += (u2 * wk[2] != 0.f);
            cnt += (m0 * wk[3] != 0.f); cnt += (m1 * wk[4] != 0.f); cnt += (m2 * wk[5] != 0.f);
            cnt += (d0 * wk[6] != 0.f); cnt += (d1 * wk[7] != 0.f); cnt += (d2 * wk[8] != 0.f);
            const int z = 9 - cnt;
#pragma unroll
            for (int k = 0; k < 10; ++k) h[k] += (z == k);
            u0 = m0; u1 = m1; u2 = m2; m0 = d0; m1 = d1; m2 = d2;
        }
    }

#pragma unroll
    for (int k = 0; k < 10; ++k) {
        int v = h[k];
        v += __shfl_xor(v, 32); v += __shfl_xor(v, 16); v += __shfl_xor(v, 8);
        v += __shfl_xor(v, 4);  v += __shfl_xor(v, 2);  v += __shfl_xor(v, 1);
        if ((tid & 63) == 0 && v != 0) atomicAdd(&lh[k], v);
    }
    __syncthreads();
    if (tid < 10 && lh[tid] > 0)
        atomicAdd(&hist[c * 10 + tid], (float)lh[tid]);
}

// ===========================================================================
extern "C" void kernel_launch(void* const* d_in, const int* in_sizes, int n_in,
                              void* d_out, int out_size, void* d_ws, size_t ws_size,
                              hipStream_t stream) {
    const float* x    = (const float*)d_in[0];
    const float* w    = (const float*)d_in[1];
    const float* bias = (const float*)d_in[2];
    float* y    = (float*)d_out;
    float* hist = (float*)d_out + CONV_OUT_ELEMS;

    const size_t XBF_OFF = 73728;                              // wbufA bytes
    const size_t ZC_OFF  = XBF_OFF + (size_t)NPIX * 64 * 2;    // 25,763,840
    const size_t ZL_OFF  = ZC_OFF + 64;
    const size_t NEED    = ZL_OFF + (size_t)ZCAP * 4;          // ~25.8 MB

    if (ws_size >= NEED) {
        unsigned short* wbufA = (unsigned short*)d_ws;          // 73728 B
        unsigned short* xbf   = (unsigned short*)((char*)d_ws + XBF_OFF);
        int* zcnt             = (int*)((char*)d_ws + ZC_OFF);
        unsigned int* zlist   = (unsigned int*)((char*)d_ws + ZL_OFF);

        hipMemsetAsync(zcnt, 0, sizeof(int), stream);
        prep_fused<<<1712, 256, 0, stream>>>(x, w, xbf, wbufA, zcnt, zlist);
        conv_fused<<<896, 256, 0, stream>>>(xbf, wbufA, bias, y);
        hist_final<<<1, 256, 0, stream>>>(x, w, zcnt, zlist, hist);
    } else {
        hipMemsetAsync(hist, 0, 64 * 10 * sizeof(float), stream);
        unsigned short* wbuf = (unsigned short*)d_ws;
        prep_weights_fb<<<144, 256, 0, stream>>>(w, wbuf);
        conv_mfma_fb<<<dim3(7, 28, 4), 256, 0, stream>>>(x, wbuf, bias, y);
        hist_v2<<<dim3(8, 64, 4), 256, 0, stream>>>(x, w, hist);
    }
}